// Round 12
// baseline (129.024 us; speedup 1.0000x reference)
//
#include <hip/hip_runtime.h>

// Gaussian mixture field evaluation via MFMA:
//   out[m] = sum_n exp2( K*q[m,n] + log2(I_n) ),  K = -0.5*log2(e)
// q = dot(P[m][0..9], C[n][0..9]) with split-f16 (hi/lo) operands ->
// 30 K-slots -> one mfma_f32_16x16x32_f16 per 16x16 q-tile.
//
// Round 12: software exp2, REASSOCIATION-PROOF. Round 11's magic-number
// range reduction ((t+1.5*2^23)-1.5*2^23) is algebraically a no-op, so an
// unsafe-FP device compile folded it away -> f=0 -> out = 2^round(t) ->
// 3.5% error. This version uses rintf (v_rndne_f32) + v_cvt_i32_f32:
// f = t - rint(t) cannot be folded under any FP mode. ldexpf handles all
// underflow (no clamp needed; t >= ~-1600 by construction).
// 11 wave-instrs per 128 elements, all full-rate VALU -- removes the
// 26 cy/wave-exp trans-pipe invariant that pinned rounds 7-10 at 43-45 us.
//
// Structure = round 9: no LDS, B-frags streamed from L2-resident 256 KiB
// bfrag; 2 point-tiles/wave; grid(512,4); atomicAdd partials.
//
// Verified gfx950 layouts (learn_hip m89/m91):
//   A-frag: lane holds A[m=lane&15][k=(lane>>4)*8+j], j=0..7
//   B-frag: lane holds B[k=(lane>>4)*8+j][n=lane&15]
//   D:      lane holds D[row=(lane>>4)*4+r][col=lane&15], r=0..3

#define M_POINTS 65536
#define N_GAUSS  4096
#define KNEG     (-0.72134752044448170f)   // -0.5 * log2(e)

typedef _Float16 half8   __attribute__((ext_vector_type(8)));
typedef float    float4v __attribute__((ext_vector_type(4)));
typedef float    v2f     __attribute__((ext_vector_type(2)));

// ---------------------------------------------------------------------------
// Packed software exp2 on a lane-pair. Full-rate VALU only:
// 2 v_rndne_f32 + 2 v_cvt_i32_f32 + 1 v_pk_add + 4 v_pk_fma + 2 v_ldexp.
// Valid for all t <= ~0.5; underflow (t < -126) handled exactly by ldexp.
// ---------------------------------------------------------------------------
__device__ __forceinline__ v2f softexp2(v2f t) {
    const float zi0 = __builtin_rintf(t.x);   // v_rndne_f32 (opaque: no folding)
    const float zi1 = __builtin_rintf(t.y);
    const int   i0  = (int)zi0;               // v_cvt_i32_f32
    const int   i1  = (int)zi1;
    v2f zi = {zi0, zi1};
    v2f f  = t - zi;                          // f in [-0.5, 0.5]

    // 2^f, degree-4 Taylor/Horner (rel err ~3e-5 on [-0.5,0.5])
    const v2f C4 = {0.00961813f, 0.00961813f};
    const v2f C3 = {0.05550411f, 0.05550411f};
    const v2f C2 = {0.24022651f, 0.24022651f};
    const v2f C1 = {0.69314718f, 0.69314718f};
    const v2f C0 = {1.0f, 1.0f};
    v2f p = __builtin_elementwise_fma(f, C4, C3);
    p = __builtin_elementwise_fma(f, p, C2);
    p = __builtin_elementwise_fma(f, p, C1);
    p = __builtin_elementwise_fma(f, p, C0);

    v2f r;
    r.x = ldexpf(p.x, i0);                    // v_ldexp_f32
    r.y = ldexpf(p.y, i1);
    return r;
}

// ---------------------------------------------------------------------------
// Kernel 1: per-gaussian coefficient precompute in MFMA B-operand fragment
// layout (bfrag[tile*64 + lane] = half8), plus d_out zeroing.
// ---------------------------------------------------------------------------
__global__ __launch_bounds__(256) void precompute_bfrag(
    const float* __restrict__ pos, const float* __restrict__ scl,
    const float* __restrict__ rot, const float* __restrict__ inten,
    half8* __restrict__ bfrag, float4* __restrict__ out_zero)
{
    int n = blockIdx.x * 256 + threadIdx.x;
    if (n >= N_GAUSS) return;

    // zero d_out: 65536 floats = 16384 float4 across 4096 threads
    {
        float4 z = make_float4(0.f, 0.f, 0.f, 0.f);
        out_zero[n]         = z;
        out_zero[n + 4096]  = z;
        out_zero[n + 8192]  = z;
        out_zero[n + 12288] = z;
    }

    float qw = rot[4*n+0], qx = rot[4*n+1], qy = rot[4*n+2], qz = rot[4*n+3];
    float nrm = sqrtf(qw*qw + qx*qx + qy*qy + qz*qz) + 1e-8f;
    float ir = 1.0f / nrm;
    qw *= ir; qx *= ir; qy *= ir; qz *= ir;

    float r00 = 1.f - 2.f*(qy*qy + qz*qz);
    float r01 = 2.f*(qx*qy - qz*qw);
    float r02 = 2.f*(qx*qz + qy*qw);
    float r10 = 2.f*(qx*qy + qz*qw);
    float r11 = 1.f - 2.f*(qx*qx + qz*qz);
    float r12 = 2.f*(qy*qz - qx*qw);
    float r20 = 2.f*(qx*qz - qy*qw);
    float r21 = 2.f*(qy*qz + qx*qw);
    float r22 = 1.f - 2.f*(qx*qx + qy*qy);

    float s0 = fabsf(scl[3*n+0]) + 1e-6f;
    float s1 = fabsf(scl[3*n+1]) + 1e-6f;
    float s2 = fabsf(scl[3*n+2]) + 1e-6f;
    float w0 = 1.f/(s0*s0), w1 = 1.f/(s1*s1), w2 = 1.f/(s2*s2);

    float a00 = r00*r00*w0 + r01*r01*w1 + r02*r02*w2;
    float a01 = r00*r10*w0 + r01*r11*w1 + r02*r12*w2;
    float a02 = r00*r20*w0 + r01*r21*w1 + r02*r22*w2;
    float a11 = r10*r10*w0 + r11*r11*w1 + r12*r12*w2;
    float a12 = r10*r20*w0 + r11*r21*w1 + r12*r22*w2;
    float a22 = r20*r20*w0 + r21*r21*w1 + r22*r22*w2;

    float p0 = pos[3*n+0], p1 = pos[3*n+1], p2 = pos[3*n+2];
    float b0 = a00*p0 + a01*p1 + a02*p2;
    float b1 = a01*p0 + a11*p1 + a12*p2;
    float b2 = a02*p0 + a12*p1 + a22*p2;
    float c  = b0*p0 + b1*p1 + b2*p2;

    float I = fmaxf(inten[n], 1e-30f);   // I=0 -> t very negative -> exp2 -> 0

    float C[10];
    C[0] = KNEG * a00;       C[1] = KNEG * a11;       C[2] = KNEG * a22;
    C[3] = 2.f*KNEG * a01;   C[4] = 2.f*KNEG * a02;   C[5] = 2.f*KNEG * a12;
    C[6] = -2.f*KNEG * b0;   C[7] = -2.f*KNEG * b1;   C[8] = -2.f*KNEG * b2;
    C[9] = KNEG * c + log2f(I);

    _Float16 chi[10], clo[10];
#pragma unroll
    for (int j = 0; j < 10; ++j) {
        chi[j] = (_Float16)C[j];
        clo[j] = (_Float16)(C[j] - (float)chi[j]);
    }

    const int tile = n >> 4, nl = n & 15;
#pragma unroll
    for (int q = 0; q < 4; ++q) {
        half8 v;
#pragma unroll
        for (int j = 0; j < 8; ++j) {
            const int k = q*8 + j;
            _Float16 h = (_Float16)0.f;
            if (k < 30) {
                const int jm = k / 3, s = k % 3;
                h = (s == 2) ? clo[jm] : chi[jm];
            }
            v[j] = h;
        }
        bfrag[tile*64 + q*16 + nl] = v;
    }
}

// ---------------------------------------------------------------------------
// A-frag builder: named scalars + first-class vectors only (SROA-proof).
// k-slot layout: k=3j -> phi_j, 3j+1 -> plo_j, 3j+2 -> phi_j; k=30,31 -> 0.
// quad q holds k = q*8 .. q*8+7.
// ---------------------------------------------------------------------------
__device__ __forceinline__ half8 build_afrag(float x, float y, float z, int q) {
    const float P0 = x*x, P1 = y*y, P2 = z*z;
    const float P3 = x*y, P4 = x*z, P5 = y*z;

    _Float16 h0 = (_Float16)P0, l0 = (_Float16)(P0 - (float)h0);
    _Float16 h1 = (_Float16)P1, l1 = (_Float16)(P1 - (float)h1);
    _Float16 h2 = (_Float16)P2, l2 = (_Float16)(P2 - (float)h2);
    _Float16 h3 = (_Float16)P3, l3 = (_Float16)(P3 - (float)h3);
    _Float16 h4 = (_Float16)P4, l4 = (_Float16)(P4 - (float)h4);
    _Float16 h5 = (_Float16)P5, l5 = (_Float16)(P5 - (float)h5);
    _Float16 h6 = (_Float16)x,  l6 = (_Float16)(x - (float)h6);
    _Float16 h7 = (_Float16)y,  l7 = (_Float16)(y - (float)h7);
    _Float16 h8 = (_Float16)z,  l8 = (_Float16)(z - (float)h8);
    const _Float16 one = (_Float16)1.f, zer = (_Float16)0.f;

    // k:       0   1   2   3   4   5   6   7
    half8 c0 = {h0, l0, h0, h1, l1, h1, h2, l2};
    // k:       8   9  10  11  12  13  14  15
    half8 c1 = {h2, h3, l3, h3, h4, l4, h4, h5};
    // k:      16  17  18  19  20  21  22  23
    half8 c2 = {l5, h5, h6, l6, h6, h7, l7, h7};
    // k:      24  25  26  27  28  29  30  31
    half8 c3 = {h8, l8, h8, one, zer, one, zer, zer};

    return (q == 0) ? c0 : (q == 1) ? c1 : (q == 2) ? c2 : c3;
}

// ---------------------------------------------------------------------------
// Kernel 2: main evaluation — no LDS, no barriers, no trans ops.
// grid(512, 4) x 256 threads (8 blocks/CU). Each wave owns TWO 16-point
// tiles and streams its 64-tile gaussian chunk from L2-resident bfrag.
// Per iter: 1 load + 2 MFMAs -> 512 pairs -> 4 softexp2 pairs + 4 pk_adds.
// atomicAdd partials (4 per output element).
// ---------------------------------------------------------------------------
#define PT_SLABS  512               // 65536 / 128 points per block
#define G_SPLIT   4
#define G_TILES   (256 / G_SPLIT)   // 64 tiles per chunk

__global__ __launch_bounds__(256) void gauss_eval(
    const float* __restrict__ pts,
    const half8* __restrict__ bfrag,
    float* __restrict__ out)
{
    const int tid  = threadIdx.x;
    const int lane = tid & 63;
    const int wv   = tid >> 6;
    const int ml   = lane & 15;          // A m-index / B n-index / D col
    const int q    = lane >> 4;          // k-group / D row-group

    const int base = blockIdx.x * 128 + wv * 32;   // first of this wave's 32 pts

    const int p0i = base + ml, p1i = base + 16 + ml;
    half8 af0 = build_afrag(pts[3*p0i], pts[3*p0i+1], pts[3*p0i+2], q);
    half8 af1 = build_afrag(pts[3*p1i], pts[3*p1i+1], pts[3*p1i+2], q);

    v2f a0lo = {0.f, 0.f}, a0hi = {0.f, 0.f};   // point-tile 0: d[0],d[1] / d[2],d[3]
    v2f a1lo = {0.f, 0.f}, a1hi = {0.f, 0.f};   // point-tile 1
    const float4v zero4 = {0.f, 0.f, 0.f, 0.f};

    // this wave's B-frag stream: 64 tiles, 1 KiB each, L2-hot
    const half8* src = bfrag + (blockIdx.y * G_TILES) * 64 + lane;

#pragma unroll 4
    for (int i = 0; i < G_TILES; ++i) {
        half8 b = src[i * 64];
        float4v d0 = __builtin_amdgcn_mfma_f32_16x16x32_f16(af0, b, zero4, 0, 0, 0);
        float4v d1 = __builtin_amdgcn_mfma_f32_16x16x32_f16(af1, b, zero4, 0, 0, 0);
        v2f t0lo = {d0[0], d0[1]}, t0hi = {d0[2], d0[3]};
        v2f t1lo = {d1[0], d1[1]}, t1hi = {d1[2], d1[3]};
        a0lo += softexp2(t0lo);   // all full-rate pk VALU
        a0hi += softexp2(t0hi);
        a1lo += softexp2(t1lo);
        a1hi += softexp2(t1hi);
    }

    // reduce over the 16 gaussian lanes within each quad
#pragma unroll
    for (int m = 1; m <= 8; m <<= 1) {
        v2f s0lo = { __shfl_xor(a0lo.x, m), __shfl_xor(a0lo.y, m) };
        v2f s0hi = { __shfl_xor(a0hi.x, m), __shfl_xor(a0hi.y, m) };
        v2f s1lo = { __shfl_xor(a1lo.x, m), __shfl_xor(a1lo.y, m) };
        v2f s1hi = { __shfl_xor(a1hi.x, m), __shfl_xor(a1hi.y, m) };
        a0lo += s0lo; a0hi += s0hi; a1lo += s1lo; a1hi += s1hi;
    }

    // lane ml==0 of quad q holds sums for points base + f*16 + q*4 + r
    if (ml == 0) {
        const int o = base + q*4;
        atomicAdd(&out[o + 0],  a0lo.x);
        atomicAdd(&out[o + 1],  a0lo.y);
        atomicAdd(&out[o + 2],  a0hi.x);
        atomicAdd(&out[o + 3],  a0hi.y);
        atomicAdd(&out[o + 16], a1lo.x);
        atomicAdd(&out[o + 17], a1lo.y);
        atomicAdd(&out[o + 18], a1hi.x);
        atomicAdd(&out[o + 19], a1hi.y);
    }
}

extern "C" void kernel_launch(void* const* d_in, const int* in_sizes, int n_in,
                              void* d_out, int out_size, void* d_ws, size_t ws_size,
                              hipStream_t stream) {
    const float* sample_points = (const float*)d_in[0];
    const float* positions     = (const float*)d_in[1];
    const float* scales        = (const float*)d_in[2];
    const float* rotations     = (const float*)d_in[3];
    const float* intensities   = (const float*)d_in[4];

    half8* bfrag = (half8*)d_ws;   // 256 KiB

    precompute_bfrag<<<N_GAUSS / 256, 256, 0, stream>>>(
        positions, scales, rotations, intensities, bfrag, (float4*)d_out);

    gauss_eval<<<dim3(PT_SLABS, G_SPLIT), 256, 0, stream>>>(
        sample_points, bfrag, (float*)d_out);
}